// Round 16
// baseline (112.846 us; speedup 1.0000x reference)
//
#include <hip/hip_runtime.h>
#include <hip/hip_fp16.h>

// GCN 2-layer, aggregate-first L1 / aggregate-last L2, fused MFMA MLP:
//   agg1 = Â x   (gather over xh = half(dis*x))
//   g2   = half(dis * (relu(agg1@W1+b1) @ W2))   (one MFMA kernel, y1 in LDS)
//   out  = relu(dis * (g2_i + sum g2_src) + b2)  (gather)
// Gather: 4 nodes/wave (16-lane groups, float2-of-half2 per lane) — one
// vector load serves 4 edge-rows. CSR build with 128-node buckets (NB=391).
// k_prep: zero bucketCnt + pre-transpose W1,W2 to fp16. N < 65536 (u16 csr).

#define THREADS 256
#define EPB 4096    // edges per partition block (16 edges/thread)
#define CAP 8192    // per-128-node-bucket capacity (mean 4092, +64 sigma)

using half8 = __attribute__((ext_vector_type(8))) _Float16;
using f32x4 = __attribute__((ext_vector_type(4))) float;

__device__ inline int block_scan256(int v, int* wsum) {
    int lane = threadIdx.x & 63, w = threadIdx.x >> 6;
    int x = v;
    #pragma unroll
    for (int off = 1; off < 64; off <<= 1) {
        int y = __shfl_up(x, off);
        if (lane >= off) x += y;
    }
    if (lane == 63) wsum[w] = x;
    __syncthreads();
    int woff = 0;
    #pragma unroll
    for (int i = 0; i < 4; ++i) if (i < w) woff += wsum[i];
    return woff + x - v;
}

__device__ inline int block_scan512(int v, int* wsum) {
    int lane = threadIdx.x & 63, w = threadIdx.x >> 6;
    int x = v;
    #pragma unroll
    for (int off = 1; off < 64; off <<= 1) {
        int y = __shfl_up(x, off);
        if (lane >= off) x += y;
    }
    if (lane == 63) wsum[w] = x;
    __syncthreads();
    int woff = 0;
    #pragma unroll
    for (int i = 0; i < 8; ++i) if (i < w) woff += wsum[i];
    return woff + x - v;
}

__global__ __launch_bounds__(256) void k_prep(const float* __restrict__ W1,
                                              const float* __restrict__ W2,
                                              int* __restrict__ bucketCnt, int NB,
                                              _Float16* __restrict__ W1t,
                                              _Float16* __restrict__ W2t) {
    int i = blockIdx.x * 256 + threadIdx.x;
    if (blockIdx.x == 0) {
        int t = threadIdx.x;
        if (t < NB) bucketCnt[t] = 0;
        if (t + 256 < NB) bucketCnt[t + 256] = 0;
    }
    if (i < 64 * 128) {              // W1 [k=64][c=128]
        int k = i >> 7, c = i & 127;
        W1t[c * 64 + k] = (_Float16)W1[i];
    } else if (i < 2 * 64 * 128) {   // W2 [k=128][c=64]
        int j = i - 64 * 128;
        int k = j >> 6, c = j & 63;
        W2t[c * 128 + k] = (_Float16)W2[j];
    }
}

__global__ __launch_bounds__(256) void k_partition(const int* __restrict__ src,
                                                   const int* __restrict__ dst,
                                                   int* __restrict__ bucketCnt,
                                                   unsigned int* __restrict__ bucketed,
                                                   int E, int NB) {
    __shared__ int hist[512];
    __shared__ int localOff[512];
    __shared__ int runBase[512];
    __shared__ int wsum[4];
    __shared__ unsigned int stage[EPB];
    int t = threadIdx.x;
    int base = blockIdx.x * EPB;
    int nE = min(EPB, E - base);
    hist[t] = 0; hist[t + 256] = 0;
    __syncthreads();
    int dreg[16], sreg[16];
    #pragma unroll
    for (int it = 0; it < 16; ++it) {
        int j = t + it * 256;
        dreg[it] = 0; sreg[it] = 0;
        if (j < nE) {
            dreg[it] = dst[base + j];
            sreg[it] = src[base + j];
            atomicAdd(&hist[dreg[it] >> 7], 1);
        }
    }
    __syncthreads();
    int v0 = hist[t];
    int v1 = hist[t + 256];
    int e0 = block_scan256(v0, wsum);
    int total1 = wsum[0] + wsum[1] + wsum[2] + wsum[3];
    __syncthreads();
    int e1 = block_scan256(v1, wsum) + total1;
    localOff[t] = e0;
    localOff[t + 256] = e1;
    if (v0 > 0 && t < NB) runBase[t] = atomicAdd(&bucketCnt[t], v0);
    if (v1 > 0 && t + 256 < NB) runBase[t + 256] = atomicAdd(&bucketCnt[t + 256], v1);
    __syncthreads();
    hist[t] = e0; hist[t + 256] = e1;  // reuse as in-block cursors
    __syncthreads();
    #pragma unroll
    for (int it = 0; it < 16; ++it) {
        int j = t + it * 256;
        if (j < nE) {
            int idx = atomicAdd(&hist[dreg[it] >> 7], 1);
            stage[idx] = ((unsigned)dreg[it] << 16) | (unsigned)sreg[it];
        }
    }
    __syncthreads();
    for (int j = t; j < nE; j += 256) {
        unsigned u = stage[j];
        int b = u >> 23;  // == dst>>7
        int slot = runBase[b] + (j - localOff[b]);
        if (slot < CAP) bucketed[(size_t)b * CAP + slot] = u;
    }
}

__global__ __launch_bounds__(512) void k_place(const unsigned int* __restrict__ bucketed,
                                               const int* __restrict__ bucketCnt,
                                               const float* __restrict__ x,
                                               unsigned short* __restrict__ csr,
                                               int* __restrict__ row_ptr,
                                               float* __restrict__ dis,
                                               __half* __restrict__ xh, int N, int NB) {
    __shared__ int nodeCnt[128];
    __shared__ int wsum[8];
    __shared__ int baseS;
    __shared__ float disS[128];
    __shared__ unsigned int bkS[CAP];
    __shared__ unsigned short outS[CAP];
    int b = blockIdx.x, t = threadIdx.x;
    {
        int v = (t < NB) ? min(bucketCnt[t], CAP) : 0;
        int excl = block_scan512(v, wsum);
        if (t == b) baseS = excl;
        __syncthreads();
    }
    int base = baseS;
    const unsigned int* bk = bucketed + (size_t)b * CAP;
    int cnt = min(bucketCnt[b], CAP);
    if (t < 128) nodeCnt[t] = 0;
    __syncthreads();
    for (int j = t; j < cnt; j += 512) {
        unsigned u = bk[j];
        bkS[j] = u;
        atomicAdd(&nodeCnt[(u >> 16) & 127], 1);
    }
    __syncthreads();
    int v = (t < 128) ? nodeCnt[t] : 0;
    int excl = block_scan512(v, wsum);
    int node = b * 128 + t;
    if (t < 128) {
        float d = rsqrtf(1.0f + (float)v);
        disS[t] = d;
        if (node < N) {
            row_ptr[node] = base + excl;
            dis[node] = d;
            if (node == N - 1) row_ptr[N] = base + excl + v;
        }
    }
    __syncthreads();
    if (t < 128) nodeCnt[t] = excl;
    __syncthreads();
    for (int j = t; j < cnt; j += 512) {
        unsigned u = bkS[j];
        int p = atomicAdd(&nodeCnt[(u >> 16) & 127], 1);
        outS[p] = (unsigned short)(u & 0xFFFF);
    }
    __syncthreads();
    for (int j = t; j < cnt; j += 512) csr[base + j] = outS[j];
    int nodes = min(128, N - b * 128);
    if (nodes > 0) {
        const float2* xp = (const float2*)(x + (size_t)b * 128 * 64);
        __half2* xhp = (__half2*)(xh + (size_t)b * 128 * 64);
        int total = nodes * 32;
        for (int i = t; i < total; i += 512) {
            float dd = disS[i >> 5];
            float2 vv = xp[i];
            xhp[i] = __floats2half2_rn(dd * vv.x, dd * vv.y);
        }
    }
}

// Gather, 4 nodes per wave: 16-lane groups; lane loads float2 (4 halves, 8B);
// 16 lanes cover one 128B row. 8-deep MLP unroll per group (32 loads/wave).
template <bool RELU, typename OutT>
__global__ __launch_bounds__(256) void k_gather64(const __half* __restrict__ gt,
                                                  const int* __restrict__ row_ptr,
                                                  const unsigned short* __restrict__ csr,
                                                  const float* __restrict__ dis,
                                                  const float* __restrict__ bias,
                                                  OutT* __restrict__ out, int n) {
    int wave = threadIdx.x >> 6, lane = threadIdx.x & 63;
    int g = lane >> 4;        // group 0..3 within wave
    int t16 = lane & 15;      // lane within group
    int hb = g * 16;          // shfl base for this group
    int node = blockIdx.x * 16 + wave * 4 + g;
    bool valid = node < n;
    int nodeC = valid ? node : (n - 1);
    int beg = row_ptr[nodeC], end = row_ptr[nodeC + 1];
    int mt = end - beg;
    const float2* gp = (const float2*)gt;  // row = 16 float2 (4 halves each)
    float2 sraw = gp[(size_t)nodeC * 16 + t16];
    float2 sv0 = __half22float2(*(const __half2*)&sraw.x);
    float2 sv1 = __half22float2(*(const __half2*)&sraw.y);
    float a0 = sv0.x, a1 = sv0.y, a2 = sv1.x, a3 = sv1.y;
    for (int base = 0; base < mt; base += 16) {
        int m = mt - base; if (m > 16) m = 16;
        int idx = csr[beg + base + (t16 < m ? t16 : m - 1)];
        int j = 0;
        for (; j + 8 <= m; j += 8) {
            int s0 = __shfl(idx, hb + j + 0), s1 = __shfl(idx, hb + j + 1);
            int s2 = __shfl(idx, hb + j + 2), s3 = __shfl(idx, hb + j + 3);
            int s4 = __shfl(idx, hb + j + 4), s5 = __shfl(idx, hb + j + 5);
            int s6 = __shfl(idx, hb + j + 6), s7 = __shfl(idx, hb + j + 7);
            float2 r0 = gp[(size_t)s0 * 16 + t16];
            float2 r1 = gp[(size_t)s1 * 16 + t16];
            float2 r2 = gp[(size_t)s2 * 16 + t16];
            float2 r3 = gp[(size_t)s3 * 16 + t16];
            float2 r4 = gp[(size_t)s4 * 16 + t16];
            float2 r5 = gp[(size_t)s5 * 16 + t16];
            float2 r6 = gp[(size_t)s6 * 16 + t16];
            float2 r7 = gp[(size_t)s7 * 16 + t16];
            float2 p0, p1;
            p0 = __half22float2(*(const __half2*)&r0.x); p1 = __half22float2(*(const __half2*)&r0.y);
            a0 += p0.x; a1 += p0.y; a2 += p1.x; a3 += p1.y;
            p0 = __half22float2(*(const __half2*)&r1.x); p1 = __half22float2(*(const __half2*)&r1.y);
            a0 += p0.x; a1 += p0.y; a2 += p1.x; a3 += p1.y;
            p0 = __half22float2(*(const __half2*)&r2.x); p1 = __half22float2(*(const __half2*)&r2.y);
            a0 += p0.x; a1 += p0.y; a2 += p1.x; a3 += p1.y;
            p0 = __half22float2(*(const __half2*)&r3.x); p1 = __half22float2(*(const __half2*)&r3.y);
            a0 += p0.x; a1 += p0.y; a2 += p1.x; a3 += p1.y;
            p0 = __half22float2(*(const __half2*)&r4.x); p1 = __half22float2(*(const __half2*)&r4.y);
            a0 += p0.x; a1 += p0.y; a2 += p1.x; a3 += p1.y;
            p0 = __half22float2(*(const __half2*)&r5.x); p1 = __half22float2(*(const __half2*)&r5.y);
            a0 += p0.x; a1 += p0.y; a2 += p1.x; a3 += p1.y;
            p0 = __half22float2(*(const __half2*)&r6.x); p1 = __half22float2(*(const __half2*)&r6.y);
            a0 += p0.x; a1 += p0.y; a2 += p1.x; a3 += p1.y;
            p0 = __half22float2(*(const __half2*)&r7.x); p1 = __half22float2(*(const __half2*)&r7.y);
            a0 += p0.x; a1 += p0.y; a2 += p1.x; a3 += p1.y;
        }
        for (; j < m; ++j) {
            int s = __shfl(idx, hb + j);
            float2 r = gp[(size_t)s * 16 + t16];
            float2 p0 = __half22float2(*(const __half2*)&r.x);
            float2 p1 = __half22float2(*(const __half2*)&r.y);
            a0 += p0.x; a1 += p0.y; a2 += p1.x; a3 += p1.y;
        }
    }
    if (valid) {
        float dd = dis[node];
        float r0 = dd * a0, r1 = dd * a1, r2 = dd * a2, r3 = dd * a3;
        int c = t16 * 4;
        if constexpr (RELU) {
            r0 = fmaxf(r0 + bias[c + 0], 0.0f);
            r1 = fmaxf(r1 + bias[c + 1], 0.0f);
            r2 = fmaxf(r2 + bias[c + 2], 0.0f);
            r3 = fmaxf(r3 + bias[c + 3], 0.0f);
        }
        if constexpr (sizeof(OutT) == 2) {
            __half2 h0 = __floats2half2_rn(r0, r1);
            __half2 h1 = __floats2half2_rn(r2, r3);
            float2 pk;
            *(__half2*)&pk.x = h0;
            *(__half2*)&pk.y = h1;
            *(float2*)((__half*)out + (size_t)node * 64 + c) = pk;
        } else {
            *(float4*)((float*)out + (size_t)node * 64 + c) = make_float4(r0, r1, r2, r3);
        }
    }
}

// Fused MFMA MLP; weights read as B-fragments from L2 (pre-transposed fp16).
__global__ __launch_bounds__(256) void k_gemm_fused(const __half* __restrict__ agg1,
                                                    const _Float16* __restrict__ W1t,
                                                    const float* __restrict__ b1,
                                                    const _Float16* __restrict__ W2t,
                                                    const float* __restrict__ dis,
                                                    __half* __restrict__ g2, int n) {
    __shared__ _Float16 aggS[64 * 72];
    __shared__ _Float16 ysS[64 * 136];
    int t = threadIdx.x;
    int w = t >> 6, l = t & 63;
    int node0 = blockIdx.x * 64;
    for (int i = t; i < 64 * 32; i += 256) {
        int r = i >> 5, c2 = i & 31;
        int node = node0 + r;
        __half2 hv = (node < n) ? ((const __half2*)agg1)[(size_t)node * 32 + c2] : __half2{};
        *(__half2*)&aggS[r * 72 + c2 * 2] = hv;
    }
    __syncthreads();
    int lr = l & 15, lk = (l >> 4) * 8;
    {
        f32x4 acc[8] = {};
        #pragma unroll
        for (int ks = 0; ks < 2; ++ks) {
            half8 af = *(const half8*)&aggS[(w * 16 + lr) * 72 + ks * 32 + lk];
            #pragma unroll
            for (int nt = 0; nt < 8; ++nt) {
                half8 bf = *(const half8*)&W1t[(nt * 16 + lr) * 64 + ks * 32 + lk];
                acc[nt] = __builtin_amdgcn_mfma_f32_16x16x32_f16(af, bf, acc[nt], 0, 0, 0);
            }
        }
        int orow = w * 16 + (l >> 4) * 4;
        #pragma unroll
        for (int r = 0; r < 4; ++r) {
            #pragma unroll
            for (int nt = 0; nt < 8; ++nt) {
                int col = nt * 16 + lr;
                ysS[(orow + r) * 136 + col] = (_Float16)fmaxf(acc[nt][r] + b1[col], 0.0f);
            }
        }
    }
    __syncthreads();
    {
        f32x4 acc[4] = {};
        #pragma unroll
        for (int ks = 0; ks < 4; ++ks) {
            half8 af = *(const half8*)&ysS[(w * 16 + lr) * 136 + ks * 32 + lk];
            #pragma unroll
            for (int nt = 0; nt < 4; ++nt) {
                half8 bf = *(const half8*)&W2t[(nt * 16 + lr) * 128 + ks * 32 + lk];
                acc[nt] = __builtin_amdgcn_mfma_f32_16x16x32_f16(af, bf, acc[nt], 0, 0, 0);
            }
        }
        int orow = w * 16 + (l >> 4) * 4;
        #pragma unroll
        for (int r = 0; r < 4; ++r) {
            int node = node0 + orow + r;
            if (node < n) {
                float dd = dis[node];
                #pragma unroll
                for (int nt = 0; nt < 4; ++nt) {
                    int col = nt * 16 + lr;
                    g2[(size_t)node * 64 + col] = __float2half(dd * acc[nt][r]);
                }
            }
        }
    }
}

static inline size_t align_up(size_t v, size_t a) { return (v + a - 1) / a * a; }

extern "C" void kernel_launch(void* const* d_in, const int* in_sizes, int n_in,
                              void* d_out, int out_size, void* d_ws, size_t ws_size,
                              hipStream_t stream) {
    const float* x  = (const float*)d_in[0];
    const int*   ei = (const int*)d_in[1];
    const float* W1 = (const float*)d_in[2];
    const float* b1 = (const float*)d_in[3];
    const float* W2 = (const float*)d_in[4];
    const float* b2 = (const float*)d_in[5];
    float* out = (float*)d_out;

    const int N = in_sizes[0] / 64;   // 50000
    const int E = in_sizes[1] / 2;    // 1600000
    const int* src = ei;
    const int* dst = ei + E;
    const int NB = (N + 127) >> 7;    // 391 buckets of 128 nodes

    char* ws = (char*)d_ws;
    size_t off = 0;
    int* bucketCnt = (int*)(ws + off);      off = align_up(off + (size_t)NB * 4, 256);
    unsigned int* bucketed = (unsigned int*)(ws + off); off = align_up(off + (size_t)NB * CAP * 4, 256);
    unsigned short* csr = (unsigned short*)(ws + off);  off = align_up(off + (size_t)E * 2, 256);
    int* row_ptr = (int*)(ws + off);        off = align_up(off + (size_t)(N + 1) * 4, 256);
    float* dis = (float*)(ws + off);        off = align_up(off + (size_t)N * 4, 256);
    __half* xh = (__half*)(ws + off);       off = align_up(off + (size_t)N * 64 * 2, 256);
    __half* agg1 = (__half*)(ws + off);     off = align_up(off + (size_t)N * 64 * 2, 256);
    __half* g2 = (__half*)(ws + off);       off = align_up(off + (size_t)N * 64 * 2, 256);
    _Float16* W1t = (_Float16*)(ws + off);  off = align_up(off + (size_t)64 * 128 * 2, 256);
    _Float16* W2t = (_Float16*)(ws + off);  off = align_up(off + (size_t)64 * 128 * 2, 256);
    (void)ws_size;

    // prep + CSR build
    k_prep<<<64, THREADS, 0, stream>>>(W1, W2, bucketCnt, NB, W1t, W2t);
    k_partition<<<(E + EPB - 1) / EPB, THREADS, 0, stream>>>(src, dst, bucketCnt, bucketed, E, NB);
    k_place<<<NB, 512, 0, stream>>>(bucketed, bucketCnt, x, csr, row_ptr, dis, xh, N, NB);

    // gather1 -> fused MFMA MLP -> gather2
    k_gather64<false, __half><<<(N + 15) / 16, THREADS, 0, stream>>>(xh, row_ptr, csr, dis, b1, agg1, N);
    k_gemm_fused<<<(N + 63) / 64, THREADS, 0, stream>>>(agg1, W1t, b1, W2t, dis, g2, N);
    k_gather64<true, float><<<(N + 15) / 16, THREADS, 0, stream>>>(g2, row_ptr, csr, dis, b2, out, N);
}

// Round 17
// 109.604 us; speedup vs baseline: 1.0296x; 1.0296x over previous
//
#include <hip/hip_runtime.h>
#include <hip/hip_fp16.h>

// GCN 2-layer, aggregate-first L1 / aggregate-last L2, fused MFMA MLP:
//   agg1 = Â x   (gather over xh = half(dis*x))
//   g2   = half(dis * (relu(agg1@W1+b1) @ W2))   (one MFMA kernel, y1 in LDS)
//   out  = relu(dis * (g2_i + sum g2_src) + b2)  (gather)
// CSR build with 128-node buckets (NB=391): partition scans 391 buckets via
// two chained 256-scans; place = 391 blocks, 48.7 KB LDS -> 2 blocks/CU.
// k_prep: zero bucketCnt + pre-transpose W1,W2 to fp16 (read from L2 as MFMA
// B-fragments). N < 65536 (u16 csr indices).
// R16 lesson: 2-nodes/wave (half2/lane) is the gather's instruction/request
// balance point; 4-nodes/wave (float2/lane) regressed. This is the R15 config.

#define THREADS 256
#define EPB 4096    // edges per partition block (16 edges/thread)
#define CAP 8192    // per-128-node-bucket capacity (mean 4092, +64 sigma)

using half8 = __attribute__((ext_vector_type(8))) _Float16;
using f32x4 = __attribute__((ext_vector_type(4))) float;

__device__ inline int block_scan256(int v, int* wsum) {
    int lane = threadIdx.x & 63, w = threadIdx.x >> 6;
    int x = v;
    #pragma unroll
    for (int off = 1; off < 64; off <<= 1) {
        int y = __shfl_up(x, off);
        if (lane >= off) x += y;
    }
    if (lane == 63) wsum[w] = x;
    __syncthreads();
    int woff = 0;
    #pragma unroll
    for (int i = 0; i < 4; ++i) if (i < w) woff += wsum[i];
    return woff + x - v;
}

__device__ inline int block_scan512(int v, int* wsum) {
    int lane = threadIdx.x & 63, w = threadIdx.x >> 6;
    int x = v;
    #pragma unroll
    for (int off = 1; off < 64; off <<= 1) {
        int y = __shfl_up(x, off);
        if (lane >= off) x += y;
    }
    if (lane == 63) wsum[w] = x;
    __syncthreads();
    int woff = 0;
    #pragma unroll
    for (int i = 0; i < 8; ++i) if (i < w) woff += wsum[i];
    return woff + x - v;
}

// zero bucketCnt (NB<=512) + transpose weights to fp16: W1t[c][k], W2t[c][k]
__global__ __launch_bounds__(256) void k_prep(const float* __restrict__ W1,
                                              const float* __restrict__ W2,
                                              int* __restrict__ bucketCnt, int NB,
                                              _Float16* __restrict__ W1t,
                                              _Float16* __restrict__ W2t) {
    int i = blockIdx.x * 256 + threadIdx.x;
    if (blockIdx.x == 0) {
        int t = threadIdx.x;
        if (t < NB) bucketCnt[t] = 0;
        if (t + 256 < NB) bucketCnt[t + 256] = 0;
    }
    if (i < 64 * 128) {              // W1 [k=64][c=128], read coalesced
        int k = i >> 7, c = i & 127;
        W1t[c * 64 + k] = (_Float16)W1[i];
    } else if (i < 2 * 64 * 128) {   // W2 [k=128][c=64]
        int j = i - 64 * 128;
        int k = j >> 6, c = j & 63;
        W2t[c * 128 + k] = (_Float16)W2[j];
    }
}

// Partition into 128-node buckets (id = dst>>7, 391 buckets).
__global__ __launch_bounds__(256) void k_partition(const int* __restrict__ src,
                                                   const int* __restrict__ dst,
                                                   int* __restrict__ bucketCnt,
                                                   unsigned int* __restrict__ bucketed,
                                                   int E, int NB) {
    __shared__ int hist[512];
    __shared__ int localOff[512];
    __shared__ int runBase[512];
    __shared__ int wsum[4];
    __shared__ unsigned int stage[EPB];
    int t = threadIdx.x;
    int base = blockIdx.x * EPB;
    int nE = min(EPB, E - base);
    hist[t] = 0; hist[t + 256] = 0;
    __syncthreads();
    int dreg[16], sreg[16];
    #pragma unroll
    for (int it = 0; it < 16; ++it) {
        int j = t + it * 256;
        dreg[it] = 0; sreg[it] = 0;
        if (j < nE) {
            dreg[it] = dst[base + j];
            sreg[it] = src[base + j];
            atomicAdd(&hist[dreg[it] >> 7], 1);
        }
    }
    __syncthreads();
    // exclusive scan over 512 entries: two chained 256-scans
    int v0 = hist[t];
    int v1 = hist[t + 256];
    int e0 = block_scan256(v0, wsum);
    int total1 = wsum[0] + wsum[1] + wsum[2] + wsum[3];
    __syncthreads();
    int e1 = block_scan256(v1, wsum) + total1;
    localOff[t] = e0;
    localOff[t + 256] = e1;
    if (v0 > 0 && t < NB) runBase[t] = atomicAdd(&bucketCnt[t], v0);
    if (v1 > 0 && t + 256 < NB) runBase[t + 256] = atomicAdd(&bucketCnt[t + 256], v1);
    __syncthreads();
    hist[t] = e0; hist[t + 256] = e1;  // reuse as in-block cursors
    __syncthreads();
    #pragma unroll
    for (int it = 0; it < 16; ++it) {
        int j = t + it * 256;
        if (j < nE) {
            int idx = atomicAdd(&hist[dreg[it] >> 7], 1);
            stage[idx] = ((unsigned)dreg[it] << 16) | (unsigned)sreg[it];
        }
    }
    __syncthreads();
    for (int j = t; j < nE; j += 256) {
        unsigned u = stage[j];
        int b = u >> 23;  // == dst>>7 (dst < 65536)
        int slot = runBase[b] + (j - localOff[b]);
        if (slot < CAP) bucketed[(size_t)b * CAP + slot] = u;
    }
}

// Per-bucket placement (128 nodes/bucket); bucket LDS-staged; 512 threads.
// LDS ~48.7 KB -> 2 blocks/CU.
__global__ __launch_bounds__(512) void k_place(const unsigned int* __restrict__ bucketed,
                                               const int* __restrict__ bucketCnt,
                                               const float* __restrict__ x,
                                               unsigned short* __restrict__ csr,
                                               int* __restrict__ row_ptr,
                                               float* __restrict__ dis,
                                               __half* __restrict__ xh, int N, int NB) {
    __shared__ int nodeCnt[128];
    __shared__ int wsum[8];
    __shared__ int baseS;
    __shared__ float disS[128];
    __shared__ unsigned int bkS[CAP];     // 32 KB
    __shared__ unsigned short outS[CAP];  // 16 KB
    int b = blockIdx.x, t = threadIdx.x;
    {
        int v = (t < NB) ? min(bucketCnt[t], CAP) : 0;
        int excl = block_scan512(v, wsum);
        if (t == b) baseS = excl;
        __syncthreads();
    }
    int base = baseS;
    const unsigned int* bk = bucketed + (size_t)b * CAP;
    int cnt = min(bucketCnt[b], CAP);
    if (t < 128) nodeCnt[t] = 0;
    __syncthreads();
    for (int j = t; j < cnt; j += 512) {
        unsigned u = bk[j];
        bkS[j] = u;
        atomicAdd(&nodeCnt[(u >> 16) & 127], 1);
    }
    __syncthreads();
    int v = (t < 128) ? nodeCnt[t] : 0;
    int excl = block_scan512(v, wsum);
    int node = b * 128 + t;
    if (t < 128) {
        float d = rsqrtf(1.0f + (float)v);
        disS[t] = d;
        if (node < N) {
            row_ptr[node] = base + excl;
            dis[node] = d;
            if (node == N - 1) row_ptr[N] = base + excl + v;
        }
    }
    __syncthreads();
    if (t < 128) nodeCnt[t] = excl;  // reuse as cursor
    __syncthreads();
    for (int j = t; j < cnt; j += 512) {
        unsigned u = bkS[j];
        int p = atomicAdd(&nodeCnt[(u >> 16) & 127], 1);
        outS[p] = (unsigned short)(u & 0xFFFF);
    }
    __syncthreads();
    for (int j = t; j < cnt; j += 512) csr[base + j] = outS[j];
    // fused cast: xh[node][:] = half(dis[node] * x[node][:]) for this bucket
    int nodes = min(128, N - b * 128);
    if (nodes > 0) {
        const float2* xp = (const float2*)(x + (size_t)b * 128 * 64);
        __half2* xhp = (__half2*)(xh + (size_t)b * 128 * 64);
        int total = nodes * 32;  // float2 units, 32 per node
        for (int i = t; i < total; i += 512) {
            float dd = disS[i >> 5];
            float2 vv = xp[i];
            xhp[i] = __floats2half2_rn(dd * vv.x, dd * vv.y);
        }
    }
}

// Gather, 2 nodes per wave, 16-deep MLP unroll.
template <bool RELU, typename OutT>
__global__ __launch_bounds__(256) void k_gather64(const __half* __restrict__ gt,
                                                  const int* __restrict__ row_ptr,
                                                  const unsigned short* __restrict__ csr,
                                                  const float* __restrict__ dis,
                                                  const float* __restrict__ bias,
                                                  OutT* __restrict__ out, int n) {
    int wave = threadIdx.x >> 6, lane = threadIdx.x & 63;
    int hb = lane & 32;
    int col2 = lane & 31;
    int node = blockIdx.x * 8 + wave * 2 + (lane >> 5);
    bool valid = node < n;
    int nodeC = valid ? node : (n - 1);
    int beg = row_ptr[nodeC], end = row_ptr[nodeC + 1];
    int mt = end - beg;
    const __half2* gp = (const __half2*)gt;
    float2 sv = __half22float2(gp[(size_t)nodeC * 32 + col2]);
    float a0 = sv.x, a1 = sv.y;
    for (int base = 0; base < mt; base += 32) {
        int m = mt - base; if (m > 32) m = 32;
        int idx = csr[beg + base + (col2 < m ? col2 : m - 1)];
        int j = 0;
        for (; j + 16 <= m; j += 16) {
            int s0 = __shfl(idx, hb + j + 0),  s1 = __shfl(idx, hb + j + 1);
            int s2 = __shfl(idx, hb + j + 2),  s3 = __shfl(idx, hb + j + 3);
            int s4 = __shfl(idx, hb + j + 4),  s5 = __shfl(idx, hb + j + 5);
            int s6 = __shfl(idx, hb + j + 6),  s7 = __shfl(idx, hb + j + 7);
            int s8 = __shfl(idx, hb + j + 8),  s9 = __shfl(idx, hb + j + 9);
            int sa = __shfl(idx, hb + j + 10), sb = __shfl(idx, hb + j + 11);
            int sc = __shfl(idx, hb + j + 12), sd = __shfl(idx, hb + j + 13);
            int se = __shfl(idx, hb + j + 14), sf = __shfl(idx, hb + j + 15);
            float2 v0 = __half22float2(gp[(size_t)s0 * 32 + col2]);
            float2 v1 = __half22float2(gp[(size_t)s1 * 32 + col2]);
            float2 v2 = __half22float2(gp[(size_t)s2 * 32 + col2]);
            float2 v3 = __half22float2(gp[(size_t)s3 * 32 + col2]);
            float2 v4 = __half22float2(gp[(size_t)s4 * 32 + col2]);
            float2 v5 = __half22float2(gp[(size_t)s5 * 32 + col2]);
            float2 v6 = __half22float2(gp[(size_t)s6 * 32 + col2]);
            float2 v7 = __half22float2(gp[(size_t)s7 * 32 + col2]);
            float2 v8 = __half22float2(gp[(size_t)s8 * 32 + col2]);
            float2 v9 = __half22float2(gp[(size_t)s9 * 32 + col2]);
            float2 va = __half22float2(gp[(size_t)sa * 32 + col2]);
            float2 vb = __half22float2(gp[(size_t)sb * 32 + col2]);
            float2 vc = __half22float2(gp[(size_t)sc * 32 + col2]);
            float2 vd = __half22float2(gp[(size_t)sd * 32 + col2]);
            float2 ve = __half22float2(gp[(size_t)se * 32 + col2]);
            float2 vf = __half22float2(gp[(size_t)sf * 32 + col2]);
            a0 += (((v0.x + v1.x) + (v2.x + v3.x)) + ((v4.x + v5.x) + (v6.x + v7.x)))
                + (((v8.x + v9.x) + (va.x + vb.x)) + ((vc.x + vd.x) + (ve.x + vf.x)));
            a1 += (((v0.y + v1.y) + (v2.y + v3.y)) + ((v4.y + v5.y) + (v6.y + v7.y)))
                + (((v8.y + v9.y) + (va.y + vb.y)) + ((vc.y + vd.y) + (ve.y + vf.y)));
        }
        for (; j + 4 <= m; j += 4) {
            int s0 = __shfl(idx, hb + j + 0), s1 = __shfl(idx, hb + j + 1);
            int s2 = __shfl(idx, hb + j + 2), s3 = __shfl(idx, hb + j + 3);
            float2 v0 = __half22float2(gp[(size_t)s0 * 32 + col2]);
            float2 v1 = __half22float2(gp[(size_t)s1 * 32 + col2]);
            float2 v2 = __half22float2(gp[(size_t)s2 * 32 + col2]);
            float2 v3 = __half22float2(gp[(size_t)s3 * 32 + col2]);
            a0 += (v0.x + v1.x) + (v2.x + v3.x);
            a1 += (v0.y + v1.y) + (v2.y + v3.y);
        }
        for (; j < m; ++j) {
            int s = __shfl(idx, hb + j);
            float2 v = __half22float2(gp[(size_t)s * 32 + col2]);
            a0 += v.x; a1 += v.y;
        }
    }
    if (valid) {
        float dd = dis[node];
        float r0 = dd * a0, r1 = dd * a1;
        if constexpr (RELU) {
            r0 = fmaxf(r0 + bias[col2 * 2], 0.0f);
            r1 = fmaxf(r1 + bias[col2 * 2 + 1], 0.0f);
        }
        if constexpr (sizeof(OutT) == 2) {
            *(__half2*)((__half*)out + (size_t)node * 64 + col2 * 2) = __floats2half2_rn(r0, r1);
        } else {
            *(float2*)((float*)out + (size_t)node * 64 + col2 * 2) = make_float2(r0, r1);
        }
    }
}

// Fused MFMA MLP; weights read as B-fragments from L2 (pre-transposed fp16).
__global__ __launch_bounds__(256) void k_gemm_fused(const __half* __restrict__ agg1,
                                                    const _Float16* __restrict__ W1t,
                                                    const float* __restrict__ b1,
                                                    const _Float16* __restrict__ W2t,
                                                    const float* __restrict__ dis,
                                                    __half* __restrict__ g2, int n) {
    __shared__ _Float16 aggS[64 * 72];
    __shared__ _Float16 ysS[64 * 136];
    int t = threadIdx.x;
    int w = t >> 6, l = t & 63;
    int node0 = blockIdx.x * 64;
    for (int i = t; i < 64 * 32; i += 256) {  // half2 units
        int r = i >> 5, c2 = i & 31;
        int node = node0 + r;
        __half2 hv = (node < n) ? ((const __half2*)agg1)[(size_t)node * 32 + c2] : __half2{};
        *(__half2*)&aggS[r * 72 + c2 * 2] = hv;
    }
    __syncthreads();
    int lr = l & 15, lk = (l >> 4) * 8;
    // phase 1: ysS = half(relu(agg @ W1 + b1))
    {
        f32x4 acc[8] = {};
        #pragma unroll
        for (int ks = 0; ks < 2; ++ks) {
            half8 af = *(const half8*)&aggS[(w * 16 + lr) * 72 + ks * 32 + lk];
            #pragma unroll
            for (int nt = 0; nt < 8; ++nt) {
                half8 bf = *(const half8*)&W1t[(nt * 16 + lr) * 64 + ks * 32 + lk];
                acc[nt] = __builtin_amdgcn_mfma_f32_16x16x32_f16(af, bf, acc[nt], 0, 0, 0);
            }
        }
        int orow = w * 16 + (l >> 4) * 4;
        #pragma unroll
        for (int r = 0; r < 4; ++r) {
            #pragma unroll
            for (int nt = 0; nt < 8; ++nt) {
                int col = nt * 16 + lr;
                ysS[(orow + r) * 136 + col] = (_Float16)fmaxf(acc[nt][r] + b1[col], 0.0f);
            }
        }
    }
    __syncthreads();
    // phase 2: g2 = half(dis * (ys @ W2))
    {
        f32x4 acc[4] = {};
        #pragma unroll
        for (int ks = 0; ks < 4; ++ks) {
            half8 af = *(const half8*)&ysS[(w * 16 + lr) * 136 + ks * 32 + lk];
            #pragma unroll
            for (int nt = 0; nt < 4; ++nt) {
                half8 bf = *(const half8*)&W2t[(nt * 16 + lr) * 128 + ks * 32 + lk];
                acc[nt] = __builtin_amdgcn_mfma_f32_16x16x32_f16(af, bf, acc[nt], 0, 0, 0);
            }
        }
        int orow = w * 16 + (l >> 4) * 4;
        #pragma unroll
        for (int r = 0; r < 4; ++r) {
            int node = node0 + orow + r;
            if (node < n) {
                float dd = dis[node];
                #pragma unroll
                for (int nt = 0; nt < 4; ++nt) {
                    int col = nt * 16 + lr;
                    g2[(size_t)node * 64 + col] = __float2half(dd * acc[nt][r]);
                }
            }
        }
    }
}

static inline size_t align_up(size_t v, size_t a) { return (v + a - 1) / a * a; }

extern "C" void kernel_launch(void* const* d_in, const int* in_sizes, int n_in,
                              void* d_out, int out_size, void* d_ws, size_t ws_size,
                              hipStream_t stream) {
    const float* x  = (const float*)d_in[0];
    const int*   ei = (const int*)d_in[1];
    const float* W1 = (const float*)d_in[2];
    const float* b1 = (const float*)d_in[3];
    const float* W2 = (const float*)d_in[4];
    const float* b2 = (const float*)d_in[5];
    float* out = (float*)d_out;

    const int N = in_sizes[0] / 64;   // 50000
    const int E = in_sizes[1] / 2;    // 1600000
    const int* src = ei;
    const int* dst = ei + E;
    const int NB = (N + 127) >> 7;    // 391 buckets of 128 nodes

    char* ws = (char*)d_ws;
    size_t off = 0;
    int* bucketCnt = (int*)(ws + off);      off = align_up(off + (size_t)NB * 4, 256);
    unsigned int* bucketed = (unsigned int*)(ws + off); off = align_up(off + (size_t)NB * CAP * 4, 256);
    unsigned short* csr = (unsigned short*)(ws + off);  off = align_up(off + (size_t)E * 2, 256);
    int* row_ptr = (int*)(ws + off);        off = align_up(off + (size_t)(N + 1) * 4, 256);
    float* dis = (float*)(ws + off);        off = align_up(off + (size_t)N * 4, 256);
    __half* xh = (__half*)(ws + off);       off = align_up(off + (size_t)N * 64 * 2, 256);
    __half* agg1 = (__half*)(ws + off);     off = align_up(off + (size_t)N * 64 * 2, 256);
    __half* g2 = (__half*)(ws + off);       off = align_up(off + (size_t)N * 64 * 2, 256);
    _Float16* W1t = (_Float16*)(ws + off);  off = align_up(off + (size_t)64 * 128 * 2, 256);
    _Float16* W2t = (_Float16*)(ws + off);  off = align_up(off + (size_t)64 * 128 * 2, 256);
    (void)ws_size;

    // prep (zero + weight transpose) + CSR build
    k_prep<<<64, THREADS, 0, stream>>>(W1, W2, bucketCnt, NB, W1t, W2t);
    k_partition<<<(E + EPB - 1) / EPB, THREADS, 0, stream>>>(src, dst, bucketCnt, bucketed, E, NB);
    k_place<<<NB, 512, 0, stream>>>(bucketed, bucketCnt, x, csr, row_ptr, dis, xh, N, NB);

    // gather1 -> fused MFMA MLP -> gather2
    k_gather64<false, __half><<<(N + 7) / 8, THREADS, 0, stream>>>(xh, row_ptr, csr, dis, b1, agg1, N);
    k_gemm_fused<<<(N + 63) / 64, THREADS, 0, stream>>>(agg1, W1t, b1, W2t, dis, g2, N);
    k_gather64<true, float><<<(N + 7) / 8, THREADS, 0, stream>>>(g2, row_ptr, csr, dis, b2, out, N);
}